// Round 20
// baseline (3079.367 us; speedup 1.0000x reference)
//
#include <hip/hip_runtime.h>
#include <hip/hip_bf16.h>

#define T_LEN 512
#define NB 64      // batch
#define FB 256     // input features
#define SB 1024    // hidden size
#define NWG 256    // persistent workgroups: (ng 0..3) x (sb 0..63)

typedef __attribute__((ext_vector_type(8))) short bf16x8;
typedef __attribute__((ext_vector_type(4))) float f32x4;
typedef __attribute__((ext_vector_type(2))) float f32x2;

#define MFMA(a, b, c) __builtin_amdgcn_mfma_f32_16x16x32_bf16((a), (b), (c), 0, 0, 0)

// device-scope (sc1) 16B fragment load as 2 relaxed agent u64 atomics
__device__ __forceinline__ bf16x8 load_frag_dev(const __hip_bfloat16* p) {
    const unsigned long long* q = (const unsigned long long*)p;
    unsigned long long a = __hip_atomic_load(q,     __ATOMIC_RELAXED, __HIP_MEMORY_SCOPE_AGENT);
    unsigned long long b = __hip_atomic_load(q + 1, __ATOMIC_RELAXED, __HIP_MEMORY_SCOPE_AGENT);
    union { unsigned long long u[2]; bf16x8 v; } r;
    r.u[0] = a; r.u[1] = b;
    return r.v;
}

// ---------------- prep: x -> MFMA A-fragment order, bf16 ----------------
// XAf[t][m(4)][kc(8)][lane*8+e] ; element = x[t][m*16+(l&15)][kc*32+8*(l>>4)+e]
__global__ void xfrag_kernel(const float* __restrict__ x, __hip_bfloat16* __restrict__ xaf) {
    int tid  = blockIdx.x * 256 + threadIdx.x;   // total T*4*8*64 = 1,048,576
    int l    = tid & 63;
    int frag = tid >> 6;                         // t*32 + m*8 + kc
    int kc   = frag & 7;
    int m    = (frag >> 3) & 3;
    int t    = frag >> 5;
    int row  = m * 16 + (l & 15);
    int k0   = kc * 32 + 8 * (l >> 4);
    const float* src = x + ((size_t)(t * NB + row)) * FB + k0;
    __hip_bfloat16* dst = xaf + (size_t)frag * 512 + l * 8;
#pragma unroll
    for (int e = 0; e < 8; ++e) dst[e] = __float2bfloat16(src[e]);
}

// ------------- prep: [Wx;Wh] -> per-(sb,wave) register-load order -------------
// WBf[sb(64)][wv(4)][kcw(10)][g(4)][lane*8+e]
// kc(wv,kcw) = kcw<2 ? wv*2+kcw : 8 + wv*8 + (kcw-2)   (x-chunks spread over waves)
// k = kc*32+8*(l>>4)+e ; s = sb*16+(l&15)
__global__ void wfrag_kernel(const float* __restrict__ Wx, const float* __restrict__ Wh,
                             __hip_bfloat16* __restrict__ wbf) {
    int tid  = blockIdx.x * 256 + threadIdx.x;   // total 64*4*10*4*64 = 655,360
    int l    = tid & 63;
    int frag = tid >> 6;                         // ((sb*4+wv)*10+kcw)*4+g
    int g    = frag & 3;
    int kcw  = (frag >> 2) % 10;
    int wv   = (frag / 40) & 3;
    int sb   = frag / 160;
    int kc   = (kcw < 2) ? (wv * 2 + kcw) : (8 + wv * 8 + (kcw - 2));
    int s    = sb * 16 + (l & 15);
    int k0   = kc * 32 + 8 * (l >> 4);
    __hip_bfloat16* dst = wbf + (size_t)frag * 512 + l * 8;
#pragma unroll
    for (int e = 0; e < 8; ++e) {
        int k = k0 + e;
        float v = (k < FB) ? Wx[((size_t)g * FB + k) * SB + s]
                           : Wh[((size_t)g * SB + (k - FB)) * SB + s];
        dst[e] = __float2bfloat16(v);
    }
}

// ---------------- persistent LSTM kernel: quarter-row WGs ----------------
// r19 (1522 us), ONE delta: ARRIVE BARRIER REMOVED. The two gate-waves (wv=0,1;
// gates live in threads 0..127) each drain their OWN h-store (vmcnt(0) -- sole
// outstanding VMEM at that point) and publish flag[t][wg][wv]. Consumers poll
// 16 producer WGs x 2 flags in one 64-lane load. Waves 2-3 run ahead into the
// next step (x-tail, poll, h-loads, MFMAs) while gate-waves finish -- jitter
// absorption the removed barrier used to forbid. part[] parity-double-buffered
// (the barrier was its WAR guard). Slot-reuse safety unchanged: h(t+1) stores
// happen after the step-t reduce barrier, which joins waves whose polls covered
// all 64 same-ng WGs at >= t-1 (done reading slot (t-3)&3).
__global__ __launch_bounds__(256, 1) void lstm_persist(
    const __hip_bfloat16* __restrict__ xaf,   // [512][4][8][512]
    const __hip_bfloat16* __restrict__ wbf,   // [64][4][10][4][512]
    const float* __restrict__ bias,           // [4][1024]
    __hip_bfloat16* __restrict__ hfrag,       // [4][32][4][512]
    float* __restrict__ cbuf,                 // [64][1024] fp32 c-state
    float* __restrict__ out,                  // [512][64][1024]
    unsigned int* __restrict__ flag,          // [512][256][2] per-gate-wave flags
    int t0, int nsteps, int use_sync)
{
    __shared__ float part[2][4 * 16 * 4 * 17];  // 2 x 17,408 B (step parity)
    const int tid = threadIdx.x;
    const int wv  = tid >> 6;
    const int l   = tid & 63;
    const int ng  = blockIdx.x >> 6;          // row-group 0..3 (16 rows)
    const int sb  = blockIdx.x & 63;
    const int lr  = l & 15;
    const int lg  = l >> 4;

    // t-1 poll: lane l -> producer WG (ng, wv*16 + (l&15)), gate-wave (l>>4)&1
    const int fidx = (ng * 64 + wv * 16 + (l & 15)) * 2 + ((l >> 4) & 1);

    // gate-phase mapping (threads 0..127): thread -> (row gn, 2 consecutive s-cols)
    const int gact = (tid < 128);
    const int gn   = (tid >> 3) & 15;         // 0..15 local row
    const int sc0  = (tid & 7) * 2;           // 0,2,..,14

    // ---- one-time: weight fragment pointers (stream from L2 every step)
    bf16x8 wf[40];
    {
        const __hip_bfloat16* wp = wbf + ((size_t)(sb * 4 + wv) * 40) * 512 + l * 8;
#pragma unroll
        for (int i = 0; i < 40; ++i) wf[i] = *reinterpret_cast<const bf16x8*>(wp + (size_t)i * 512);
    }
    // ---- one-time: bias + c-state for this thread's (gn, sc0..sc0+1)
    float br[8];
    f32x2 creg = {0.f, 0.f};
    if (gact) {
#pragma unroll
        for (int g = 0; g < 4; ++g) {
            br[g * 2]     = bias[g * SB + sb * 16 + sc0];
            br[g * 2 + 1] = bias[g * SB + sb * 16 + sc0 + 1];
        }
        creg = *reinterpret_cast<const f32x2*>(
            &cbuf[(ng * 16 + gn) * SB + sb * 16 + sc0]);
    }

    f32x4 acc[4];
    // ---- prologue: x-part of first step (h-independent)
#pragma unroll
    for (int g = 0; g < 4; ++g) acc[g] = (f32x4){0.f, 0.f, 0.f, 0.f};
    {
        const __hip_bfloat16* xs = xaf + (size_t)t0 * 16384;
#pragma unroll
        for (int j = 0; j < 2; ++j) {
            int kc = wv * 2 + j;
            bf16x8 a = *reinterpret_cast<const bf16x8*>(xs + (size_t)(ng * 8 + kc) * 512 + l * 8);
#pragma unroll
            for (int g = 0; g < 4; ++g) acc[g] = MFMA(a, wf[j * 4 + g], acc[g]);
        }
    }

    for (int tt = 0; tt < nsteps; ++tt) {
        const int t  = t0 + tt;
        const int pb = t & 1;

        if (use_sync && tt > 0) {
            // critical wait: 16 producer WGs x 2 gate-wave flags at t-1
            const unsigned int* f1 = flag + (size_t)(t - 1) * 512;
            for (;;) {
                unsigned a = __hip_atomic_load(&f1[fidx], __ATOMIC_RELAXED, __HIP_MEMORY_SCOPE_AGENT);
                if (__all(a != 0)) break;
            }
            asm volatile("" ::: "memory");   // no load motion across the wait
        }

        // ---- h-part MFMAs (8 sc1 fragment loads, compiler-batched)
        const __hip_bfloat16* hs = hfrag + (size_t)(t & 3) * 65536;
#pragma unroll
        for (int j = 0; j < 8; ++j) {
            int kch = wv * 8 + j;
            bf16x8 a = load_frag_dev(hs + (size_t)(kch * 4 + ng) * 512 + l * 8);
#pragma unroll
            for (int g = 0; g < 4; ++g) acc[g] = MFMA(a, wf[(2 + j) * 4 + g], acc[g]);
        }

        // ---- cross-wave K-reduce via parity-double-buffered LDS
#pragma unroll
        for (int g = 0; g < 4; ++g)
#pragma unroll
            for (int i = 0; i < 4; ++i)
                part[pb][((wv * 16 + lg * 4 + i) * 4 + g) * 17 + lr] = acc[g][i];
        __syncthreads();   // the ONLY barrier per step

        // ---- gates + state update: threads 0..127 (waves 0,1)
        if (gact) {
            float z[4][2];
#pragma unroll
            for (int g = 0; g < 4; ++g) {
                float s0 = 0.f, s1 = 0.f;
#pragma unroll
                for (int w2 = 0; w2 < 4; ++w2) {
                    const float* pr = &part[pb][((w2 * 16 + gn) * 4 + g) * 17 + sc0];
                    s0 += pr[0];
                    s1 += pr[1];
                }
                z[g][0] = s0 + br[g * 2];
                z[g][1] = s1 + br[g * 2 + 1];
            }
            float hv[2];
#pragma unroll
            for (int e = 0; e < 2; ++e) {
                float ig = 1.f / (1.f + expf(-z[0][e]));
                float fg = 1.f / (1.f + expf(-z[1][e]));
                float gg = tanhf(z[2][e]);
                float og = 1.f / (1.f + expf(-z[3][e]));
                float c  = fg * creg[e] + ig * gg;
                hv[e]    = og * tanhf(c);
                creg[e]  = c;
            }
            // h-frag: one sc1 u32 store (2 packed bf16)
            unsigned u0 = (unsigned)__bfloat16_as_ushort(__float2bfloat16(hv[0]));
            unsigned u1 = (unsigned)__bfloat16_as_ushort(__float2bfloat16(hv[1]));
            int sg0  = sb * 16 + sc0;
            int kch  = sg0 >> 5;
            int k8   = sg0 & 31;
            int lane = (k8 >> 3) * 16 + gn;   // row within this WG's m-tile = gn
            unsigned int* hd = reinterpret_cast<unsigned int*>(
                hfrag + (size_t)((t + 1) & 3) * 65536
                + (size_t)(kch * 4 + ng) * 512 + lane * 8 + (k8 & 7));
            __hip_atomic_store(hd, u0 | (u1 << 16), __ATOMIC_RELAXED, __HIP_MEMORY_SCOPE_AGENT);

            // per-gate-wave arrive: drain own h-store, lane-0 publishes flag
            if (use_sync) {
                asm volatile("s_waitcnt vmcnt(0)" ::: "memory");
                if (l == 0)
                    __hip_atomic_store(&flag[((size_t)t * 256 + blockIdx.x) * 2 + wv], 1u,
                                       __ATOMIC_RELAXED, __HIP_MEMORY_SCOPE_AGENT);
            }

            // out-store AFTER the flag (off the signal path)
            *reinterpret_cast<f32x2*>(
                &out[(size_t)t * (NB * SB) + (size_t)(ng * 16 + gn) * SB + sg0])
                = (f32x2){hv[0], hv[1]};
        }

        // ---- tail: x-part of next step (h-independent; waves 2-3 reach this
        //      immediately after the reduce barrier and run ahead)
        if (tt + 1 < nsteps) {
#pragma unroll
            for (int g = 0; g < 4; ++g) acc[g] = (f32x4){0.f, 0.f, 0.f, 0.f};
            const __hip_bfloat16* xs = xaf + (size_t)(t + 1) * 16384;
#pragma unroll
            for (int j = 0; j < 2; ++j) {
                int kc = wv * 2 + j;
                bf16x8 a = *reinterpret_cast<const bf16x8*>(xs + (size_t)(ng * 8 + kc) * 512 + l * 8);
#pragma unroll
                for (int g = 0; g < 4; ++g) acc[g] = MFMA(a, wf[j * 4 + g], acc[g]);
            }
        }
    }

    // ---- persist c-state (needed for the per-step fallback path)
    if (gact)
        *reinterpret_cast<f32x2*>(&cbuf[(ng * 16 + gn) * SB + sb * 16 + sc0]) = creg;
}

extern "C" void kernel_launch(void* const* d_in, const int* in_sizes, int n_in,
                              void* d_out, int out_size, void* d_ws, size_t ws_size,
                              hipStream_t stream) {
    const float* x  = (const float*)d_in[0];   // [512][64][256]
    const float* Wx = (const float*)d_in[1];   // [4][256][1024]
    const float* Wh = (const float*)d_in[2];   // [4][1024][1024]
    const float* b  = (const float*)d_in[3];   // [4][1024]
    float* out = (float*)d_out;                // [512][64][1024]

    char* ws = (char*)d_ws;
    __hip_bfloat16* xaf   = (__hip_bfloat16*)ws;                 // 16,777,216 B
    __hip_bfloat16* wbf   = (__hip_bfloat16*)(ws + 16777216);    // 10,485,760 B
    __hip_bfloat16* hfrag = (__hip_bfloat16*)(ws + 27262976);    //    524,288 B (4 bufs)
    float*          cbuf  = (float*)(ws + 27787264);             //    262,144 B
    unsigned int*   flag  = (unsigned int*)(ws + 28049408);      //  1,048,576 B

    hipLaunchKernelGGL(xfrag_kernel, dim3(4096), dim3(256), 0, stream, x, xaf);
    hipLaunchKernelGGL(wfrag_kernel, dim3(2560), dim3(256), 0, stream, Wx, Wh, wbf);
    hipMemsetAsync(hfrag, 0, 524288, stream);   // h[-1] = 0
    hipMemsetAsync(cbuf, 0, 262144, stream);    // c[-1] = 0
    hipMemsetAsync(flag, 0, 1048576, stream);   // per-step per-gate-wave flags

    const __hip_bfloat16* p_xaf = xaf;
    const __hip_bfloat16* p_wbf = wbf;
    const float* p_bias = b;
    __hip_bfloat16* p_hfrag = hfrag;
    float* p_cbuf = cbuf;
    float* p_out = out;
    unsigned int* p_flag = flag;
    int z0 = 0, ns = T_LEN, us = 1;
    void* args[] = {&p_xaf, &p_wbf, &p_bias, &p_hfrag, &p_cbuf, &p_out, &p_flag, &z0, &ns, &us};
    hipError_t err = hipLaunchCooperativeKernel((void*)lstm_persist, dim3(NWG), dim3(256),
                                                args, 0, stream);
    if (err != hipSuccess) {
        // fallback: per-step plain launches (kernel boundaries order memory)
        for (int t = 0; t < T_LEN; ++t) {
            hipLaunchKernelGGL(lstm_persist, dim3(NWG), dim3(256), 0, stream,
                               xaf, wbf, b, hfrag, cbuf, out, flag, t, 1, 0);
        }
    }
}

// Round 21
// 1267.061 us; speedup vs baseline: 2.4303x; 2.4303x over previous
//
#include <hip/hip_runtime.h>
#include <hip/hip_bf16.h>

#define T_LEN 512
#define NB 64      // batch
#define FB 256     // input features
#define SB 1024    // hidden size
#define NWG 256    // persistent workgroups: (ng 0..3) x (sb 0..63)

typedef __attribute__((ext_vector_type(8))) short bf16x8;
typedef __attribute__((ext_vector_type(4))) float f32x4;

#define MFMA(a, b, c) __builtin_amdgcn_mfma_f32_16x16x32_bf16((a), (b), (c), 0, 0, 0)

__device__ __forceinline__ float fast_sigmoid(float z) {
    return 1.f / (1.f + __expf(-z));          // v_exp_f32-based
}
__device__ __forceinline__ float fast_tanh(float z) {
    return 1.f - 2.f / (1.f + __expf(2.f * z));  // exact saturation at +-inf
}

// device-scope (sc1) 16B fragment load as 2 relaxed agent u64 atomics
__device__ __forceinline__ bf16x8 load_frag_dev(const __hip_bfloat16* p) {
    const unsigned long long* q = (const unsigned long long*)p;
    unsigned long long a = __hip_atomic_load(q,     __ATOMIC_RELAXED, __HIP_MEMORY_SCOPE_AGENT);
    unsigned long long b = __hip_atomic_load(q + 1, __ATOMIC_RELAXED, __HIP_MEMORY_SCOPE_AGENT);
    union { unsigned long long u[2]; bf16x8 v; } r;
    r.u[0] = a; r.u[1] = b;
    return r.v;
}

// ---------------- prep: x -> MFMA A-fragment order, bf16 ----------------
// XAf[t][m(4)][kc(8)][lane*8+e] ; element = x[t][m*16+(l&15)][kc*32+8*(l>>4)+e]
__global__ void xfrag_kernel(const float* __restrict__ x, __hip_bfloat16* __restrict__ xaf) {
    int tid  = blockIdx.x * 256 + threadIdx.x;   // total T*4*8*64 = 1,048,576
    int l    = tid & 63;
    int frag = tid >> 6;                         // t*32 + m*8 + kc
    int kc   = frag & 7;
    int m    = (frag >> 3) & 3;
    int t    = frag >> 5;
    int row  = m * 16 + (l & 15);
    int k0   = kc * 32 + 8 * (l >> 4);
    const float* src = x + ((size_t)(t * NB + row)) * FB + k0;
    __hip_bfloat16* dst = xaf + (size_t)frag * 512 + l * 8;
#pragma unroll
    for (int e = 0; e < 8; ++e) dst[e] = __float2bfloat16(src[e]);
}

// ------------- prep: [Wx;Wh] -> per-(sb,wave) register-load order -------------
// WBf[sb(64)][wv(4)][kcw(10)][g(4)][lane*8+e]
// kc(wv,kcw) = kcw<2 ? wv*2+kcw : 8 + wv*8 + (kcw-2)   (x-chunks spread over waves)
// k = kc*32+8*(l>>4)+e ; s = sb*16+(l&15)
__global__ void wfrag_kernel(const float* __restrict__ Wx, const float* __restrict__ Wh,
                             __hip_bfloat16* __restrict__ wbf) {
    int tid  = blockIdx.x * 256 + threadIdx.x;   // total 64*4*10*4*64 = 655,360
    int l    = tid & 63;
    int frag = tid >> 6;                         // ((sb*4+wv)*10+kcw)*4+g
    int g    = frag & 3;
    int kcw  = (frag >> 2) % 10;
    int wv   = (frag / 40) & 3;
    int sb   = frag / 160;
    int kc   = (kcw < 2) ? (wv * 2 + kcw) : (8 + wv * 8 + (kcw - 2));
    int s    = sb * 16 + (l & 15);
    int k0   = kc * 32 + 8 * (l >> 4);
    __hip_bfloat16* dst = wbf + (size_t)frag * 512 + l * 8;
#pragma unroll
    for (int e = 0; e < 8; ++e) {
        int k = k0 + e;
        float v = (k < FB) ? Wx[((size_t)g * FB + k) * SB + s]
                           : Wh[((size_t)g * SB + (k - FB)) * SB + s];
        dst[e] = __float2bfloat16(v);
    }
}

// ---------------- persistent LSTM kernel: quarter-row WGs ----------------
// r19 (1522 us), TWO gate-phase deltas (sync protocol untouched):
// (1) gates spread over ALL 256 threads, 1 element each (was 128 x 2):
//     serial gate latency halved (16 LDS reads + 6 transcendentals/thread).
// (2) fast transcendentals: sigmoid/tanh via __expf (v_exp_f32) instead of
//     range-reduced libm expf/tanhf (~30 instrs each) -- the gate phase sits
//     on the signal path between the two barriers.
__global__ __launch_bounds__(256, 1) void lstm_persist(
    const __hip_bfloat16* __restrict__ xaf,   // [512][4][8][512]
    const __hip_bfloat16* __restrict__ wbf,   // [64][4][10][4][512]
    const float* __restrict__ bias,           // [4][1024]
    __hip_bfloat16* __restrict__ hfrag,       // [4][32][4][512]
    float* __restrict__ cbuf,                 // [64][1024] fp32 c-state
    float* __restrict__ out,                  // [512][64][1024]
    unsigned int* __restrict__ flag,          // [512][256][2] (8B-padded per-WG flags)
    int t0, int nsteps, int use_sync)
{
    __shared__ float part[4 * 16 * 4 * 17];   // 17,408 B: ((wv*16+n)*4+g)*17 + sc
    const int tid = threadIdx.x;
    const int wv  = tid >> 6;
    const int l   = tid & 63;
    const int ng  = blockIdx.x >> 6;          // row-group 0..3 (16 rows)
    const int sb  = blockIdx.x & 63;
    const int lr  = l & 15;
    const int lg  = l >> 4;

    // t-1 poll: lane l -> producer WG (ng, wv*16 + (l&15))  [4-way broadcast]
    const int fidx = (ng * 64 + wv * 16 + (l & 15)) * 2;

    // gate-phase mapping (ALL 256 threads): thread -> (row gn, col sc), 1 element
    const int gn = tid >> 4;                  // 0..15 local row
    const int sc = tid & 15;                  // 0..15 local col

    // ---- one-time: weight fragment pointers (stream from L2 every step)
    bf16x8 wf[40];
    {
        const __hip_bfloat16* wp = wbf + ((size_t)(sb * 4 + wv) * 40) * 512 + l * 8;
#pragma unroll
        for (int i = 0; i < 40; ++i) wf[i] = *reinterpret_cast<const bf16x8*>(wp + (size_t)i * 512);
    }
    // ---- one-time: bias + c-state for this thread's (gn, sc)
    float br[4];
#pragma unroll
    for (int g = 0; g < 4; ++g) br[g] = bias[g * SB + sb * 16 + sc];
    float creg = cbuf[(ng * 16 + gn) * SB + sb * 16 + sc];

    // h-store position (2-byte): fragment (kch*4+ng), halfword lane*8+e
    const int k8   = 16 * (sb & 1) + sc;
    const int lane = (k8 >> 3) * 16 + gn;
    const size_t hoff = (size_t)((sb >> 1) * 4 + ng) * 512 + lane * 8 + (k8 & 7);

    f32x4 acc[4];
    // ---- prologue: x-part of first step (h-independent)
#pragma unroll
    for (int g = 0; g < 4; ++g) acc[g] = (f32x4){0.f, 0.f, 0.f, 0.f};
    {
        const __hip_bfloat16* xs = xaf + (size_t)t0 * 16384;
#pragma unroll
        for (int j = 0; j < 2; ++j) {
            int kc = wv * 2 + j;
            bf16x8 a = *reinterpret_cast<const bf16x8*>(xs + (size_t)(ng * 8 + kc) * 512 + l * 8);
#pragma unroll
            for (int g = 0; g < 4; ++g) acc[g] = MFMA(a, wf[j * 4 + g], acc[g]);
        }
    }

    for (int tt = 0; tt < nsteps; ++tt) {
        const int t = t0 + tt;

        if (use_sync && tt > 0) {
            // critical wait: my 16 producers arrived at t-1 (h[t] cols ready)
            const unsigned int* f1 = flag + (size_t)(t - 1) * 512;
            for (;;) {
                unsigned a = __hip_atomic_load(&f1[fidx], __ATOMIC_RELAXED, __HIP_MEMORY_SCOPE_AGENT);
                if (__all(a != 0)) break;
            }
            asm volatile("" ::: "memory");   // no load motion across the wait
        }

        // ---- h-part MFMAs (8 sc1 fragment loads, compiler-batched)
        const __hip_bfloat16* hs = hfrag + (size_t)(t & 3) * 65536;
#pragma unroll
        for (int j = 0; j < 8; ++j) {
            int kch = wv * 8 + j;
            bf16x8 a = load_frag_dev(hs + (size_t)(kch * 4 + ng) * 512 + l * 8);
#pragma unroll
            for (int g = 0; g < 4; ++g) acc[g] = MFMA(a, wf[(2 + j) * 4 + g], acc[g]);
        }

        // ---- cross-wave K-reduce via LDS
#pragma unroll
        for (int g = 0; g < 4; ++g)
#pragma unroll
            for (int i = 0; i < 4; ++i)
                part[((wv * 16 + lg * 4 + i) * 4 + g) * 17 + lr] = acc[g][i];
        __syncthreads();

        // ---- gates + state update: ALL 256 threads, 1 element (gn, sc)
        float hv;
        {
            float z[4];
#pragma unroll
            for (int g = 0; g < 4; ++g) {
                float s = 0.f;
#pragma unroll
                for (int w2 = 0; w2 < 4; ++w2)
                    s += part[((w2 * 16 + gn) * 4 + g) * 17 + sc];
                z[g] = s + br[g];
            }
            float ig = fast_sigmoid(z[0]);
            float fg = fast_sigmoid(z[1]);
            float gg = fast_tanh(z[2]);
            float og = fast_sigmoid(z[3]);
            float c  = fg * creg + ig * gg;
            hv       = og * fast_tanh(c);
            creg     = c;
            // h-frag: one 2-byte sc1 store (the only store in the pre-flag drain)
            unsigned short hu = __bfloat16_as_ushort(__float2bfloat16(hv));
            unsigned short* hd = reinterpret_cast<unsigned short*>(
                hfrag + (size_t)((t + 1) & 3) * 65536) + hoff;
            __hip_atomic_store(hd, hu, __ATOMIC_RELAXED, __HIP_MEMORY_SCOPE_AGENT);
        }

        // ---- arrive: barrier drains h-stores, then tid0 flag
        if (use_sync) {
            __syncthreads();
            if (tid == 0)
                __hip_atomic_store(&flag[((size_t)t * 256 + blockIdx.x) * 2], 1u,
                                   __ATOMIC_RELAXED, __HIP_MEMORY_SCOPE_AGENT);
        }

        // ---- out-store AFTER the flag (off the signal path)
        out[(size_t)t * (NB * SB) + (size_t)(ng * 16 + gn) * SB + sb * 16 + sc] = hv;

        // ---- tail: x-part of next step (h-independent, hides wait latency)
        if (tt + 1 < nsteps) {
#pragma unroll
            for (int g = 0; g < 4; ++g) acc[g] = (f32x4){0.f, 0.f, 0.f, 0.f};
            const __hip_bfloat16* xs = xaf + (size_t)(t + 1) * 16384;
#pragma unroll
            for (int j = 0; j < 2; ++j) {
                int kc = wv * 2 + j;
                bf16x8 a = *reinterpret_cast<const bf16x8*>(xs + (size_t)(ng * 8 + kc) * 512 + l * 8);
#pragma unroll
                for (int g = 0; g < 4; ++g) acc[g] = MFMA(a, wf[j * 4 + g], acc[g]);
            }
        }
    }

    // ---- persist c-state (needed for the per-step fallback path)
    cbuf[(ng * 16 + gn) * SB + sb * 16 + sc] = creg;
}

extern "C" void kernel_launch(void* const* d_in, const int* in_sizes, int n_in,
                              void* d_out, int out_size, void* d_ws, size_t ws_size,
                              hipStream_t stream) {
    const float* x  = (const float*)d_in[0];   // [512][64][256]
    const float* Wx = (const float*)d_in[1];   // [4][256][1024]
    const float* Wh = (const float*)d_in[2];   // [4][1024][1024]
    const float* b  = (const float*)d_in[3];   // [4][1024]
    float* out = (float*)d_out;                // [512][64][1024]

    char* ws = (char*)d_ws;
    __hip_bfloat16* xaf   = (__hip_bfloat16*)ws;                 // 16,777,216 B
    __hip_bfloat16* wbf   = (__hip_bfloat16*)(ws + 16777216);    // 10,485,760 B
    __hip_bfloat16* hfrag = (__hip_bfloat16*)(ws + 27262976);    //    524,288 B (4 bufs)
    float*          cbuf  = (float*)(ws + 27787264);             //    262,144 B
    unsigned int*   flag  = (unsigned int*)(ws + 28049408);      //  1,048,576 B

    hipLaunchKernelGGL(xfrag_kernel, dim3(4096), dim3(256), 0, stream, x, xaf);
    hipLaunchKernelGGL(wfrag_kernel, dim3(2560), dim3(256), 0, stream, Wx, Wh, wbf);
    hipMemsetAsync(hfrag, 0, 524288, stream);   // h[-1] = 0
    hipMemsetAsync(cbuf, 0, 262144, stream);    // c[-1] = 0
    hipMemsetAsync(flag, 0, 1048576, stream);   // per-step per-WG flags

    const __hip_bfloat16* p_xaf = xaf;
    const __hip_bfloat16* p_wbf = wbf;
    const float* p_bias = b;
    __hip_bfloat16* p_hfrag = hfrag;
    float* p_cbuf = cbuf;
    float* p_out = out;
    unsigned int* p_flag = flag;
    int z0 = 0, ns = T_LEN, us = 1;
    void* args[] = {&p_xaf, &p_wbf, &p_bias, &p_hfrag, &p_cbuf, &p_out, &p_flag, &z0, &ns, &us};
    hipError_t err = hipLaunchCooperativeKernel((void*)lstm_persist, dim3(NWG), dim3(256),
                                                args, 0, stream);
    if (err != hipSuccess) {
        // fallback: per-step plain launches (kernel boundaries order memory)
        for (int t = 0; t < T_LEN; ++t) {
            hipLaunchKernelGGL(lstm_persist, dim3(NWG), dim3(256), 0, stream,
                               xaf, wbf, b, hfrag, cbuf, out, flag, t, 1, 0);
        }
    }
}